// Round 3
// baseline (3469.349 us; speedup 1.0000x reference)
//
#include <hip/hip_runtime.h>
#include <math.h>

constexpr int B_ = 4;
constexpr int N_ = 512;

// ---------------------------------------------------------------------------
// Bit-faithful XLA:CPU Cephes f32 exp/log - VERIFIED bit-exact round 5.
// DO NOT CHANGE the arithmetic here.
// ---------------------------------------------------------------------------
__device__ __forceinline__ float cephes_expf(float xin) {
#pragma clang fp contract(off)
    float x = fminf(xin, 88.3762626647950f);
    x = fmaxf(x, -88.3762626647949f);
    float fx = x * 1.44269504088896341f;
    fx = fx + 0.5f;
    fx = floorf(fx);
    float tmp = fx * 0.693359375f;
    float z0  = fx * -2.12194440e-4f;
    float r = x - tmp;
    r = r - z0;
    float zz = r * r;
    float y = 1.9875691500E-4f;
    y = y * r + 1.3981999507E-3f;
    y = y * r + 8.3334519073E-3f;
    y = y * r + 4.1665795894E-2f;
    y = y * r + 1.6666665459E-1f;
    y = y * r + 5.0000001201E-1f;
    y = y * zz + r;
    y = y + 1.0f;
    int n = (int)fx;
    float p2n = __uint_as_float((unsigned)(n + 0x7f) << 23);
    float res = y * p2n;
    return fmaxf(res, xin);
}

__device__ __forceinline__ float cephes_logf(float t) {
#pragma clang fp contract(off)
    float xx = fmaxf(t, 1.17549435e-38f);
    unsigned u = __float_as_uint(xx);
    int e_i = (int)(u >> 23) - 0x7f;
    float e = (float)e_i + 1.0f;
    float m = __uint_as_float((u & 0x807fffffu) | 0x3f000000u);
    int mask = (m < 0.707106781186547524f);
    float tmp1 = mask ? m : 0.0f;
    float x = m - 1.0f;
    e = e - (mask ? 1.0f : 0.0f);
    x = x + tmp1;
    float z = x * x;
    float y = 7.0376836292E-2f;
    y = y * x + -1.1514610310E-1f;
    y = y * x + 1.1676998740E-1f;
    y = y * x + -1.2420140846E-1f;
    y = y * x + 1.4249322787E-1f;
    y = y * x + -1.6668057665E-1f;
    y = y * x + 2.0000714765E-1f;
    y = y * x + -2.4999993993E-1f;
    y = y * x + 3.3333331174E-1f;
    y = y * x;
    y = y * z;
    y = e * -2.12194440e-4f + y;
    y = y - z * 0.5f;
    float res = x + y;
    res = res + e * 0.693359375f;
    return res;
}

// ---------------------------------------------------------------------------
// Kernel 0 / Kernel 1: cost matrix - bit-exact, verified round 5. UNCHANGED.
// ---------------------------------------------------------------------------
__global__ __launch_bounds__(256) void class_cost_kernel(
    const float* __restrict__ logits, float* __restrict__ cc_out)
{
#pragma clang fp contract(off)
    int idx = blockIdx.x * 256 + threadIdx.x;
    if (idx >= B_ * N_) return;
    float x    = logits[idx];
    float e    = cephes_expf(-x);
    float prob = 1.0f / (1.0f + e);
    float om   = 1.0f - prob;
    float p2   = prob * prob;
    float o2   = om * om;
    float lneg = cephes_logf(om   + 1e-8f);
    float lpos = cephes_logf(prob + 1e-8f);
    float neg  = (0.75f * p2) * (-lneg);
    float pos  = (0.25f * o2) * (-lpos);
    cc_out[idx] = pos - neg;
}

__global__ __launch_bounds__(512) void cost_kernel(
    const float* __restrict__ cc,
    const float* __restrict__ pred_pts,
    const float* __restrict__ gt_pts,
    float* __restrict__ C)
{
    int blk = blockIdx.x;
    int b = blk >> 9;
    int i = blk & (N_ - 1);
    int j = threadIdx.x;

    const float2* pp2 = reinterpret_cast<const float2*>(pred_pts);
    const float2* gp2 = reinterpret_cast<const float2*>(gt_pts);
    float2 pp = pp2[b * N_ + i];
    float2 gp = gp2[b * N_ + j];
    float coord = fabsf(pp.x - gp.x) + fabsf(pp.y - gp.y);

    C[(size_t)b * N_ * N_ + (size_t)i * N_ + j] = cc[blk] + coord;
}

// ---------------------------------------------------------------------------
// DPP / lane helpers (network verified rounds 6-12).
// ---------------------------------------------------------------------------
template<int CTRL>
__device__ __forceinline__ uint32_t dpp32(uint32_t x) {
    return (uint32_t)__builtin_amdgcn_update_dpp((int)x, (int)x, CTRL, 0xF, 0xF, false);
}
#define UMINSTEP(X, CTRL) { uint32_t o_ = dpp32<CTRL>(X); X = (o_ < X) ? o_ : X; }

__device__ __forceinline__ uint32_t wave_umin_lane63(uint32_t x) {
    UMINSTEP(x, 0x111) UMINSTEP(x, 0x112) UMINSTEP(x, 0x114)
    UMINSTEP(x, 0x118) UMINSTEP(x, 0x142) UMINSTEP(x, 0x143)
    return x;
}

__device__ __forceinline__ double readlane_f64(double d, int lane) {
    unsigned long long ll = (unsigned long long)__double_as_longlong(d);
    unsigned lo = (unsigned)__builtin_amdgcn_readlane((int)(unsigned)ll, lane);
    unsigned hi = (unsigned)__builtin_amdgcn_readlane((int)(unsigned)(ll >> 32), lane);
    return __longlong_as_double((long long)(((unsigned long long)hi << 32) | lo));
}

// ---------------------------------------------------------------------------
// Kernel 2: reference _lsa replica. ROUND 17: TWO batches interleaved per
// wave (2 blocks x 1 wave). Model: per-step VALU issue ~890 cyc (round-15
// serialization measurement), wall ~1270 cyc -> ~30% latency bubbles.
// Two independent branchless walks in one basic block let the scheduler
// fill one batch's bubbles with the other's issue -> target ~890 cyc/step.
// Per-batch arithmetic order is byte-identical to the round-11 verified
// walk; changes are control-structure only:
//   - tie-break reduce always runs both phases (bit-identical result)
//   - terminal-vs-hop unified via selects (u/v masked adds unchanged;
//     ROW_SCALARS(next) before updates is exact: fetched row is never in
//     the current chain_m - same invariant the hop path already used)
//   - finished batch keeps stepping harmlessly (all columns owned =>
//     owner>=0 => p frozen); loop exits when both batches done.
// ---------------------------------------------------------------------------
#define SEL8F(sl, x0,x1,x2,x3,x4,x5,x6,x7, out) {                      \
    float a0_=((sl)&1)?(x1):(x0), a1_=((sl)&1)?(x3):(x2);              \
    float a2_=((sl)&1)?(x5):(x4), a3_=((sl)&1)?(x7):(x6);              \
    float b0_=((sl)&2)?a1_:a0_,   b1_=((sl)&2)?a3_:a2_;                \
    out = ((sl)&4)?b1_:b0_; }
#define SEL8I(sl, x0,x1,x2,x3,x4,x5,x6,x7, out) {                      \
    int a0_=((sl)&1)?(x1):(x0), a1_=((sl)&1)?(x3):(x2);                \
    int a2_=((sl)&1)?(x5):(x4), a3_=((sl)&1)?(x7):(x6);                \
    int b0_=((sl)&2)?a1_:a0_,   b1_=((sl)&2)?a3_:a2_;                  \
    out = ((sl)&4)?b1_:b0_; }
#define SEL8D(sl, x0,x1,x2,x3,x4,x5,x6,x7, out) {                      \
    double a0_=((sl)&1)?(x1):(x0), a1_=((sl)&1)?(x3):(x2);             \
    double a2_=((sl)&1)?(x5):(x4), a3_=((sl)&1)?(x7):(x6);             \
    double b0_=((sl)&2)?a1_:a0_,   b1_=((sl)&2)?a3_:a2_;               \
    out = ((sl)&4)?b1_:b0_; }

#define DECL_LOAD(S, b)                                                       \
    const float2* pq##S = reinterpret_cast<const float2*>(pred_pts) + (b) * N_; \
    const float2* gq##S = reinterpret_cast<const float2*>(gt_pts)   + (b) * N_; \
    const float*  cq##S = cc_in + (b) * N_;                                   \
    float2 r0##S = pq##S[base+0], r1##S = pq##S[base+1];                      \
    float2 r2##S = pq##S[base+2], r3##S = pq##S[base+3];                      \
    float2 r4##S = pq##S[base+4], r5##S = pq##S[base+5];                      \
    float2 r6##S = pq##S[base+6], r7##S = pq##S[base+7];                      \
    float2 g0##S = gq##S[base+0], g1##S = gq##S[base+1];                      \
    float2 g2##S = gq##S[base+2], g3##S = gq##S[base+3];                      \
    float2 g4##S = gq##S[base+4], g5##S = gq##S[base+5];                      \
    float2 g6##S = gq##S[base+6], g7##S = gq##S[base+7];                      \
    float  c0##S = cq##S[base+0], c1##S = cq##S[base+1];                      \
    float  c2##S = cq##S[base+2], c3##S = cq##S[base+3];                      \
    float  c4##S = cq##S[base+4], c5##S = cq##S[base+5];                      \
    float  c6##S = cq##S[base+6], c7##S = cq##S[base+7];                      \
    double u0##S=0.0,u1##S=0.0,u2##S=0.0,u3##S=0.0;                           \
    double u4##S=0.0,u5##S=0.0,u6##S=0.0,u7##S=0.0;                           \
    double v0##S=0.0,v1##S=0.0,v2##S=0.0,v3##S=0.0;                           \
    double v4##S=0.0,v5##S=0.0,v6##S=0.0,v7##S=0.0;                           \
    int    p0##S=-1,p1##S=-1,p2##S=-1,p3##S=-1;                               \
    int    p4##S=-1,p5##S=-1,p6##S=-1,p7##S=-1;                               \
    unsigned used_m##S = 0u;                                                  \
    unsigned chain_m##S = (t == 0) ? 1u : 0u;                                 \
    int i##S = 0;                                                             \
    float px_r##S, py_r##S, cc_r##S; double urow##S;

#define ROW_SCALARS_S(S, r) {                                                 \
    int sl_ = (r) & 7, ln_ = (r) >> 3;                                        \
    float sx_, sy_, sc_; double su_;                                          \
    SEL8F(sl_, r0##S.x,r1##S.x,r2##S.x,r3##S.x,r4##S.x,r5##S.x,r6##S.x,r7##S.x, sx_); \
    SEL8F(sl_, r0##S.y,r1##S.y,r2##S.y,r3##S.y,r4##S.y,r5##S.y,r6##S.y,r7##S.y, sy_); \
    SEL8F(sl_, c0##S,c1##S,c2##S,c3##S,c4##S,c5##S,c6##S,c7##S, sc_);         \
    SEL8D(sl_, u0##S,u1##S,u2##S,u3##S,u4##S,u5##S,u6##S,u7##S, su_);         \
    px_r##S = __uint_as_float((unsigned)__builtin_amdgcn_readlane(            \
                  (int)__float_as_uint(sx_), ln_));                           \
    py_r##S = __uint_as_float((unsigned)__builtin_amdgcn_readlane(            \
                  (int)__float_as_uint(sy_), ln_));                           \
    cc_r##S = __uint_as_float((unsigned)__builtin_amdgcn_readlane(            \
                  (int)__float_as_uint(sc_), ln_));                           \
    urow##S = readlane_f64(su_, ln_); }

#define STEP(S) {                                                             \
    float w0 = cc_r##S + (fabsf(px_r##S - g0##S.x) + fabsf(py_r##S - g0##S.y)); \
    float w1 = cc_r##S + (fabsf(px_r##S - g1##S.x) + fabsf(py_r##S - g1##S.y)); \
    float w2 = cc_r##S + (fabsf(px_r##S - g2##S.x) + fabsf(py_r##S - g2##S.y)); \
    float w3 = cc_r##S + (fabsf(px_r##S - g3##S.x) + fabsf(py_r##S - g3##S.y)); \
    float w4 = cc_r##S + (fabsf(px_r##S - g4##S.x) + fabsf(py_r##S - g4##S.y)); \
    float w5 = cc_r##S + (fabsf(px_r##S - g5##S.x) + fabsf(py_r##S - g5##S.y)); \
    float w6 = cc_r##S + (fabsf(px_r##S - g6##S.x) + fabsf(py_r##S - g6##S.y)); \
    float w7 = cc_r##S + (fabsf(px_r##S - g7##S.x) + fabsf(py_r##S - g7##S.y)); \
    w0 = (used_m##S & 0x01u) ? INF32 : w0;                                    \
    w1 = (used_m##S & 0x02u) ? INF32 : w1;                                    \
    w2 = (used_m##S & 0x04u) ? INF32 : w2;                                    \
    w3 = (used_m##S & 0x08u) ? INF32 : w3;                                    \
    w4 = (used_m##S & 0x10u) ? INF32 : w4;                                    \
    w5 = (used_m##S & 0x20u) ? INF32 : w5;                                    \
    w6 = (used_m##S & 0x40u) ? INF32 : w6;                                    \
    w7 = (used_m##S & 0x80u) ? INF32 : w7;                                    \
    double d0 = ((double)w0 - urow##S) - v0##S;                               \
    double d1 = ((double)w1 - urow##S) - v1##S;                               \
    double d2 = ((double)w2 - urow##S) - v2##S;                               \
    double d3 = ((double)w3 - urow##S) - v3##S;                               \
    double d4 = ((double)w4 - urow##S) - v4##S;                               \
    double d5 = ((double)w5 - urow##S) - v5##S;                               \
    double d6 = ((double)w6 - urow##S) - v6##S;                               \
    double d7 = ((double)w7 - urow##S) - v7##S;                               \
    double  ka = (d1 < d0) ? d1 : d0;  uint32_t sa = (d1 < d0) ? 1u : 0u;     \
    double  kb = (d3 < d2) ? d3 : d2;  uint32_t sb = (d3 < d2) ? 3u : 2u;     \
    double  kx = (d5 < d4) ? d5 : d4;  uint32_t sx = (d5 < d4) ? 5u : 4u;     \
    double  kd = (d7 < d6) ? d7 : d6;  uint32_t sd = (d7 < d6) ? 7u : 6u;     \
    double  ke = (kb < ka) ? kb : ka;  uint32_t se = (kb < ka) ? sb : sa;     \
    double  kf = (kd < kx) ? kd : kx;  uint32_t sf = (kd < kx) ? sd : sx;     \
    double  bv = (kf < ke) ? kf : ke;  uint32_t bslot = (kf < ke) ? sf : se;  \
    uint64_t kb64 = (uint64_t)__double_as_longlong(bv);                       \
    kb64 ^= (kb64 >> 63) ? 0xFFFFFFFFFFFFFFFFull : 0x8000000000000000ull;     \
    uint32_t khi = (uint32_t)(kb64 >> 32);                                    \
    uint32_t klo = (uint32_t)kb64;                                            \
    int own_pre;                                                              \
    SEL8I(bslot, p0##S,p1##S,p2##S,p3##S,p4##S,p5##S,p6##S,p7##S, own_pre);   \
    uint32_t Mhi = (uint32_t)__builtin_amdgcn_readlane(                       \
                       (int)wave_umin_lane63(khi), 63);                       \
    uint32_t kl2 = (khi == Mhi) ? klo : 0xFFFFFFFFu;                          \
    uint32_t Mlo = (uint32_t)__builtin_amdgcn_readlane(                       \
                       (int)wave_umin_lane63(kl2), 63);                       \
    int lane1 = (int)__builtin_ctzll(__ballot(khi == Mhi && klo == Mlo));     \
    int slot1 = __builtin_amdgcn_readlane((int)bslot, lane1);                 \
    int owner = __builtin_amdgcn_readlane(own_pre, lane1);                    \
    uint64_t M = ((uint64_t)Mhi << 32) | Mlo;                                 \
    uint64_t db = (M >> 63) ? (M ^ 0x8000000000000000ull) : ~M;               \
    double delta = __longlong_as_double((long long)db);                       \
    int terminal = (owner < 0) ? 1 : 0;                                       \
    int nxt  = terminal ? (i##S + 1) : owner;                                 \
    int nxtc = (nxt > (N_ - 1)) ? (N_ - 1) : nxt;                             \
    ROW_SCALARS_S(S, nxtc);                                                   \
    u0##S += (chain_m##S & 0x01u) ? delta : 0.0;                              \
    u1##S += (chain_m##S & 0x02u) ? delta : 0.0;                              \
    u2##S += (chain_m##S & 0x04u) ? delta : 0.0;                              \
    u3##S += (chain_m##S & 0x08u) ? delta : 0.0;                              \
    u4##S += (chain_m##S & 0x10u) ? delta : 0.0;                              \
    u5##S += (chain_m##S & 0x20u) ? delta : 0.0;                              \
    u6##S += (chain_m##S & 0x40u) ? delta : 0.0;                              \
    u7##S += (chain_m##S & 0x80u) ? delta : 0.0;                              \
    v0##S -= (used_m##S  & 0x01u) ? delta : 0.0;                              \
    v1##S -= (used_m##S  & 0x02u) ? delta : 0.0;                              \
    v2##S -= (used_m##S  & 0x04u) ? delta : 0.0;                              \
    v3##S -= (used_m##S  & 0x08u) ? delta : 0.0;                              \
    v4##S -= (used_m##S  & 0x10u) ? delta : 0.0;                              \
    v5##S -= (used_m##S  & 0x20u) ? delta : 0.0;                              \
    v6##S -= (used_m##S  & 0x40u) ? delta : 0.0;                              \
    v7##S -= (used_m##S  & 0x80u) ? delta : 0.0;                              \
    bool mine = (t == lane1);                                                 \
    p0##S = (terminal && mine && slot1 == 0) ? i##S : p0##S;                  \
    p1##S = (terminal && mine && slot1 == 1) ? i##S : p1##S;                  \
    p2##S = (terminal && mine && slot1 == 2) ? i##S : p2##S;                  \
    p3##S = (terminal && mine && slot1 == 3) ? i##S : p3##S;                  \
    p4##S = (terminal && mine && slot1 == 4) ? i##S : p4##S;                  \
    p5##S = (terminal && mine && slot1 == 5) ? i##S : p5##S;                  \
    p6##S = (terminal && mine && slot1 == 6) ? i##S : p6##S;                  \
    p7##S = (terminal && mine && slot1 == 7) ? i##S : p7##S;                  \
    unsigned hopbit = (t == (nxt >> 3)) ? (1u << (nxt & 7)) : 0u;             \
    unsigned selbit = mine ? (1u << slot1) : 0u;                              \
    chain_m##S = terminal ? hopbit : (chain_m##S | hopbit);                   \
    used_m##S  = terminal ? 0u     : (used_m##S  | selbit);                   \
    i##S += terminal;                                                         \
}

__global__ __launch_bounds__(64, 1) void solve_kernel(
    const float* __restrict__ cc_in,
    const float* __restrict__ pred_pts,
    const float* __restrict__ gt_pts,
    float* __restrict__ pred_idx,
    float* __restrict__ gt_idx)
{
#pragma clang fp contract(off)
    const int t  = threadIdx.x;
    const int bA = blockIdx.x * 2;
    const int bB = bA + 1;
    const int base = t << 3;
    const float INF32 = __uint_as_float(0x7F800000u);

    DECL_LOAD(A, bA)
    DECL_LOAD(B, bB)

    #pragma unroll
    for (int k = 0; k < 8; ++k) {
        pred_idx[bA * N_ + t + 64 * k] = (float)(t + 64 * k);
        pred_idx[bB * N_ + t + 64 * k] = (float)(t + 64 * k);
    }

    ROW_SCALARS_S(A, 0)
    ROW_SCALARS_S(B, 0)

    for (;;) {
        STEP(A)
        STEP(B)
        if (iA >= N_ && iB >= N_) break;
    }

    // col_of_row[p_col[j]] = j   (j = 8t + k)
    gt_idx[bA * N_ + p0A] = (float)(base);
    gt_idx[bA * N_ + p1A] = (float)(base + 1);
    gt_idx[bA * N_ + p2A] = (float)(base + 2);
    gt_idx[bA * N_ + p3A] = (float)(base + 3);
    gt_idx[bA * N_ + p4A] = (float)(base + 4);
    gt_idx[bA * N_ + p5A] = (float)(base + 5);
    gt_idx[bA * N_ + p6A] = (float)(base + 6);
    gt_idx[bA * N_ + p7A] = (float)(base + 7);

    gt_idx[bB * N_ + p0B] = (float)(base);
    gt_idx[bB * N_ + p1B] = (float)(base + 1);
    gt_idx[bB * N_ + p2B] = (float)(base + 2);
    gt_idx[bB * N_ + p3B] = (float)(base + 3);
    gt_idx[bB * N_ + p4B] = (float)(base + 4);
    gt_idx[bB * N_ + p5B] = (float)(base + 5);
    gt_idx[bB * N_ + p6B] = (float)(base + 6);
    gt_idx[bB * N_ + p7B] = (float)(base + 7);
}

// ---------------------------------------------------------------------------
extern "C" void kernel_launch(void* const* d_in, const int* in_sizes, int n_in,
                              void* d_out, int out_size, void* d_ws, size_t ws_size,
                              hipStream_t stream)
{
    const float* logits   = (const float*)d_in[0];   // (B,N)   f32
    const float* pred_pts = (const float*)d_in[1];   // (B,N,2) f32
    const float* gt_pts   = (const float*)d_in[2];   // (B,N,2) f32
    // d_in[3] = gt_mask (all true) - unused

    float* out      = (float*)d_out;
    float* pred_idx = out;                    // B*N
    float* gt_idx   = out + B_ * N_;          // B*N
    float* C        = out + 2 * B_ * N_;      // B*N*N
    float* cc       = (float*)d_ws;           // B*N scratch

    class_cost_kernel<<<(B_ * N_ + 255) / 256, 256, 0, stream>>>(logits, cc);
    cost_kernel<<<B_ * N_, N_, 0, stream>>>(cc, pred_pts, gt_pts, C);
    // 2 blocks x 1 wave; each wave interleaves two independent batch walks
    solve_kernel<<<B_ / 2, 64, 0, stream>>>(cc, pred_pts, gt_pts, pred_idx, gt_idx);
}

// Round 4
// 1635.002 us; speedup vs baseline: 2.1219x; 2.1219x over previous
//
#include <hip/hip_runtime.h>
#include <math.h>

constexpr int B_ = 4;
constexpr int N_ = 512;

// ---------------------------------------------------------------------------
// Bit-faithful XLA:CPU Cephes f32 exp/log - VERIFIED bit-exact round 5.
// DO NOT CHANGE the arithmetic here.
// ---------------------------------------------------------------------------
__device__ __forceinline__ float cephes_expf(float xin) {
#pragma clang fp contract(off)
    float x = fminf(xin, 88.3762626647950f);
    x = fmaxf(x, -88.3762626647949f);
    float fx = x * 1.44269504088896341f;
    fx = fx + 0.5f;
    fx = floorf(fx);
    float tmp = fx * 0.693359375f;
    float z0  = fx * -2.12194440e-4f;
    float r = x - tmp;
    r = r - z0;
    float zz = r * r;
    float y = 1.9875691500E-4f;
    y = y * r + 1.3981999507E-3f;
    y = y * r + 8.3334519073E-3f;
    y = y * r + 4.1665795894E-2f;
    y = y * r + 1.6666665459E-1f;
    y = y * r + 5.0000001201E-1f;
    y = y * zz + r;
    y = y + 1.0f;
    int n = (int)fx;
    float p2n = __uint_as_float((unsigned)(n + 0x7f) << 23);
    float res = y * p2n;
    return fmaxf(res, xin);
}

__device__ __forceinline__ float cephes_logf(float t) {
#pragma clang fp contract(off)
    float xx = fmaxf(t, 1.17549435e-38f);
    unsigned u = __float_as_uint(xx);
    int e_i = (int)(u >> 23) - 0x7f;
    float e = (float)e_i + 1.0f;
    float m = __uint_as_float((u & 0x807fffffu) | 0x3f000000u);
    int mask = (m < 0.707106781186547524f);
    float tmp1 = mask ? m : 0.0f;
    float x = m - 1.0f;
    e = e - (mask ? 1.0f : 0.0f);
    x = x + tmp1;
    float z = x * x;
    float y = 7.0376836292E-2f;
    y = y * x + -1.1514610310E-1f;
    y = y * x + 1.1676998740E-1f;
    y = y * x + -1.2420140846E-1f;
    y = y * x + 1.4249322787E-1f;
    y = y * x + -1.6668057665E-1f;
    y = y * x + 2.0000714765E-1f;
    y = y * x + -2.4999993993E-1f;
    y = y * x + 3.3333331174E-1f;
    y = y * x;
    y = y * z;
    y = e * -2.12194440e-4f + y;
    y = y - z * 0.5f;
    float res = x + y;
    res = res + e * 0.693359375f;
    return res;
}

// ---------------------------------------------------------------------------
// Kernel 0 / Kernel 1: cost matrix - bit-exact, verified round 5. UNCHANGED.
// ---------------------------------------------------------------------------
__global__ __launch_bounds__(256) void class_cost_kernel(
    const float* __restrict__ logits, float* __restrict__ cc_out)
{
#pragma clang fp contract(off)
    int idx = blockIdx.x * 256 + threadIdx.x;
    if (idx >= B_ * N_) return;
    float x    = logits[idx];
    float e    = cephes_expf(-x);
    float prob = 1.0f / (1.0f + e);
    float om   = 1.0f - prob;
    float p2   = prob * prob;
    float o2   = om * om;
    float lneg = cephes_logf(om   + 1e-8f);
    float lpos = cephes_logf(prob + 1e-8f);
    float neg  = (0.75f * p2) * (-lneg);
    float pos  = (0.25f * o2) * (-lpos);
    cc_out[idx] = pos - neg;
}

__global__ __launch_bounds__(512) void cost_kernel(
    const float* __restrict__ cc,
    const float* __restrict__ pred_pts,
    const float* __restrict__ gt_pts,
    float* __restrict__ C)
{
    int blk = blockIdx.x;
    int b = blk >> 9;
    int i = blk & (N_ - 1);
    int j = threadIdx.x;

    const float2* pp2 = reinterpret_cast<const float2*>(pred_pts);
    const float2* gp2 = reinterpret_cast<const float2*>(gt_pts);
    float2 pp = pp2[b * N_ + i];
    float2 gp = gp2[b * N_ + j];
    float coord = fabsf(pp.x - gp.x) + fabsf(pp.y - gp.y);

    C[(size_t)b * N_ * N_ + (size_t)i * N_ + j] = cc[blk] + coord;
}

// ---------------------------------------------------------------------------
// DPP / lane helpers (network verified rounds 6-12).
// ---------------------------------------------------------------------------
template<int CTRL>
__device__ __forceinline__ uint32_t dpp32(uint32_t x) {
    return (uint32_t)__builtin_amdgcn_update_dpp((int)x, (int)x, CTRL, 0xF, 0xF, false);
}
#define UMINSTEP(X, CTRL) { uint32_t o_ = dpp32<CTRL>(X); X = (o_ < X) ? o_ : X; }

__device__ __forceinline__ uint32_t wave_umin_lane63(uint32_t x) {
    UMINSTEP(x, 0x111) UMINSTEP(x, 0x112) UMINSTEP(x, 0x114)
    UMINSTEP(x, 0x118) UMINSTEP(x, 0x142) UMINSTEP(x, 0x143)
    return x;
}

__device__ __forceinline__ double readlane_f64(double d, int lane) {
    unsigned long long ll = (unsigned long long)__double_as_longlong(d);
    unsigned lo = (unsigned)__builtin_amdgcn_readlane((int)(unsigned)ll, lane);
    unsigned hi = (unsigned)__builtin_amdgcn_readlane((int)(unsigned)(ll >> 32), lane);
    return __longlong_as_double((long long)(((unsigned long long)hi << 32) | lo));
}

// ---------------------------------------------------------------------------
// Kernel 2: reference _lsa replica, one wave per batch, ZERO memory ops in
// the walk loop. ROUND 18 NOTES:
// - Interleave family CLOSED by measurement: per-step issue = 890 cyc
//   (round-15: 4 waves/SIMD wall = exactly 4x890), solo wall = 1270 cyc.
//   Any 2-walks-per-issue-port scheme costs max(2x890,...) = 1780 > 1270.
//   Round-17's LDS_Block_Size=512 additionally showed register spill.
// - This round, two bit-identical-by-construction issue cuts:
//   (1) u/v masked delta via sign-extended bitfield AND (bfe+2*and) instead
//       of and+cmp+2*cndmask per slot; addend is {+0.0, delta} either way.
//   (2) ROW_SCALARS: sl_ is wave-uniform -> 3-level SCALAR branch to the
//       right register + direct readlanes, replacing ~35 VALU select ops.
// ---------------------------------------------------------------------------
__global__ __launch_bounds__(64, 1) void solve_kernel(
    const float* __restrict__ cc_in,
    const float* __restrict__ pred_pts,
    const float* __restrict__ gt_pts,
    float* __restrict__ pred_idx,
    float* __restrict__ gt_idx)
{
    const int b = blockIdx.x;
    const int t = threadIdx.x;

    // ---- load generators into registers (one-time)
    const float2* pq = reinterpret_cast<const float2*>(pred_pts) + b * N_;
    const float2* gq = reinterpret_cast<const float2*>(gt_pts)   + b * N_;
    const float*  cq = cc_in + b * N_;
    const int base = t << 3;

    float2 r0 = pq[base + 0], r1 = pq[base + 1], r2 = pq[base + 2], r3 = pq[base + 3];
    float2 r4 = pq[base + 4], r5 = pq[base + 5], r6 = pq[base + 6], r7 = pq[base + 7];
    float2 g0 = gq[base + 0], g1 = gq[base + 1], g2 = gq[base + 2], g3 = gq[base + 3];
    float2 g4 = gq[base + 4], g5 = gq[base + 5], g6 = gq[base + 6], g7 = gq[base + 7];
    float  c0 = cq[base + 0], c1 = cq[base + 1], c2 = cq[base + 2], c3 = cq[base + 3];
    float  c4 = cq[base + 4], c5 = cq[base + 5], c6 = cq[base + 6], c7 = cq[base + 7];

    double u0=0.0,u1=0.0,u2=0.0,u3=0.0,u4=0.0,u5=0.0,u6=0.0,u7=0.0;
    double v0=0.0,v1=0.0,v2=0.0,v3=0.0,v4=0.0,v5=0.0,v6=0.0,v7=0.0;
    int    p0=-1,p1=-1,p2=-1,p3=-1,p4=-1,p5=-1,p6=-1,p7=-1;

    #pragma unroll
    for (int k = 0; k < 8; ++k)
        pred_idx[b * N_ + t + 64 * k] = (float)(t + 64 * k);

    #define SEL8I(sl, x0,x1,x2,x3,x4,x5,x6,x7, out) {                      \
        int a0_=((sl)&1)?(x1):(x0), a1_=((sl)&1)?(x3):(x2);                \
        int a2_=((sl)&1)?(x5):(x4), a3_=((sl)&1)?(x7):(x6);                \
        int b0_=((sl)&2)?a1_:a0_,   b1_=((sl)&2)?a3_:a2_;                  \
        out = ((sl)&4)?b1_:b0_; }

    float px_r, py_r, cc_r; double urow;

    // readlane helper for f32 registers
    #define RL_F(reg, ln) __uint_as_float((unsigned)__builtin_amdgcn_readlane( \
                              (int)__float_as_uint(reg), (ln)))
    // one arm: pull row scalars from the slot-s register set, lane ln
    #define ROW_ARM(s, ln) {                                               \
        px_r = RL_F(r##s.x, (ln)); py_r = RL_F(r##s.y, (ln));              \
        cc_r = RL_F(c##s,   (ln)); urow = readlane_f64(u##s, (ln)); }
    // sl_ is wave-uniform (loop var or readlane result) -> SCALAR branches
    #define ROW_SCALARS(r) {                                               \
        int sl_ = (r) & 7, ln_ = (r) >> 3;                                 \
        if (sl_ < 4) {                                                     \
            if (sl_ < 2) { if (sl_ == 0) ROW_ARM(0, ln_) else ROW_ARM(1, ln_) } \
            else         { if (sl_ == 2) ROW_ARM(2, ln_) else ROW_ARM(3, ln_) } \
        } else {                                                           \
            if (sl_ < 6) { if (sl_ == 4) ROW_ARM(4, ln_) else ROW_ARM(5, ln_) } \
            else         { if (sl_ == 6) ROW_ARM(6, ln_) else ROW_ARM(7, ln_) } \
        } }

    // masked-delta update: addend bits = delta_bits AND sext(mask bit k).
    // Bit-identical to (mask&bit)?delta:0.0 - addend is {+0.0, delta} both ways.
    #define UPDU(uvar, mask, k) {                                          \
        unsigned f_ = (unsigned)((int)((mask) << (31 - (k))) >> 31);       \
        uvar += __longlong_as_double((long long)(                          \
            (((unsigned long long)(dhi_ & f_)) << 32) | (dlo_ & f_))); }
    #define UPDV(vvar, mask, k) {                                          \
        unsigned f_ = (unsigned)((int)((mask) << (31 - (k))) >> 31);       \
        vvar -= __longlong_as_double((long long)(                          \
            (((unsigned long long)(dhi_ & f_)) << 32) | (dlo_ & f_))); }

    const float INF32 = __uint_as_float(0x7F800000u);

    for (int i = 0; i < N_; ++i) {
        unsigned used_m  = 0u;
        unsigned chain_m = (t == (i >> 3)) ? (1u << (i & 7)) : 0u;
        ROW_SCALARS(i);

        for (;;) {
#pragma clang fp contract(off)
            // ---- recompute this row's 8 C values (bit-equal to cost_kernel)
            float w0 = cc_r + (fabsf(px_r - g0.x) + fabsf(py_r - g0.y));
            float w1 = cc_r + (fabsf(px_r - g1.x) + fabsf(py_r - g1.y));
            float w2 = cc_r + (fabsf(px_r - g2.x) + fabsf(py_r - g2.y));
            float w3 = cc_r + (fabsf(px_r - g3.x) + fabsf(py_r - g3.y));
            float w4 = cc_r + (fabsf(px_r - g4.x) + fabsf(py_r - g4.y));
            float w5 = cc_r + (fabsf(px_r - g5.x) + fabsf(py_r - g5.y));
            float w6 = cc_r + (fabsf(px_r - g6.x) + fabsf(py_r - g6.y));
            float w7 = cc_r + (fabsf(px_r - g7.x) + fabsf(py_r - g7.y));
            w0 = (used_m & 0x01u) ? INF32 : w0;
            w1 = (used_m & 0x02u) ? INF32 : w1;
            w2 = (used_m & 0x04u) ? INF32 : w2;
            w3 = (used_m & 0x08u) ? INF32 : w3;
            w4 = (used_m & 0x10u) ? INF32 : w4;
            w5 = (used_m & 0x20u) ? INF32 : w5;
            w6 = (used_m & 0x40u) ? INF32 : w6;
            w7 = (used_m & 0x80u) ? INF32 : w7;

            // ---- f64 candidates (reference order: (c - u) - v)
            double d0 = ((double)w0 - urow) - v0;
            double d1 = ((double)w1 - urow) - v1;
            double d2 = ((double)w2 - urow) - v2;
            double d3 = ((double)w3 - urow) - v3;
            double d4 = ((double)w4 - urow) - v4;
            double d5 = ((double)w5 - urow) - v5;
            double d6 = ((double)w6 - urow) - v6;
            double d7 = ((double)w7 - urow) - v7;

            // ---- local 8->1 f64 tree (strict <, ties -> lower slot)
            double  ka = (d1 < d0) ? d1 : d0;  uint32_t sa = (d1 < d0) ? 1u : 0u;
            double  kb = (d3 < d2) ? d3 : d2;  uint32_t sb = (d3 < d2) ? 3u : 2u;
            double  kx = (d5 < d4) ? d5 : d4;  uint32_t sx = (d5 < d4) ? 5u : 4u;
            double  kd = (d7 < d6) ? d7 : d6;  uint32_t sd = (d7 < d6) ? 7u : 6u;
            double  ke = (kb < ka) ? kb : ka;  uint32_t se = (kb < ka) ? sb : sa;
            double  kf = (kd < kx) ? kd : kx;  uint32_t sf = (kd < kx) ? sd : sx;
            double  bv = (kf < ke) ? kf : ke;  uint32_t bslot = (kf < ke) ? sf : se;

            // ---- sortable key of the lane-best (order(key) == order(f64))
            uint64_t kb64 = (uint64_t)__double_as_longlong(bv);
            kb64 ^= (kb64 >> 63) ? 0xFFFFFFFFFFFFFFFFull : 0x8000000000000000ull;
            uint32_t khi = (uint32_t)(kb64 >> 32);
            uint32_t klo = (uint32_t)kb64;

            // ---- per-lane owner pre-select (overlaps the reduce)
            int own_pre;
            SEL8I(bslot, p0,p1,p2,p3,p4,p5,p6,p7, own_pre);

            // ---- phase A: wave min of hi32
            uint32_t Mhi = (uint32_t)__builtin_amdgcn_readlane(
                               (int)wave_umin_lane63(khi), 63);
            unsigned long long tied_hi = __ballot(khi == Mhi);

            int lane1; uint32_t Mlo;
            if (__builtin_popcountll(tied_hi) == 1) {      // unique hi-min
                lane1 = (int)__builtin_ctzll(tied_hi);
                Mlo = (uint32_t)__builtin_amdgcn_readlane((int)klo, lane1);
            } else {                                       // phase B on lo32
                uint32_t kl2 = (khi == Mhi) ? klo : 0xFFFFFFFFu;
                Mlo = (uint32_t)__builtin_amdgcn_readlane(
                          (int)wave_umin_lane63(kl2), 63);
                lane1 = (int)__builtin_ctzll(__ballot(khi == Mhi && klo == Mlo));
            }

            int slot1 = __builtin_amdgcn_readlane((int)bslot, lane1);
            int owner = __builtin_amdgcn_readlane(own_pre, lane1);

            // ---- delta = min value (inverse key map; wave-uniform)
            uint64_t M = ((uint64_t)Mhi << 32) | Mlo;
            uint64_t db = (M >> 63) ? (M ^ 0x8000000000000000ull) : ~M;
            double delta = __longlong_as_double((long long)db);
            const unsigned dlo_ = (unsigned)(unsigned long long)__double_as_longlong(delta);
            const unsigned dhi_ = (unsigned)(((unsigned long long)__double_as_longlong(delta)) >> 32);

            if (owner < 0) {     // free column: terminal updates + assign
                UPDU(u0, chain_m, 0) UPDU(u1, chain_m, 1)
                UPDU(u2, chain_m, 2) UPDU(u3, chain_m, 3)
                UPDU(u4, chain_m, 4) UPDU(u5, chain_m, 5)
                UPDU(u6, chain_m, 6) UPDU(u7, chain_m, 7)
                UPDV(v0, used_m, 0) UPDV(v1, used_m, 1)
                UPDV(v2, used_m, 2) UPDV(v3, used_m, 3)
                UPDV(v4, used_m, 4) UPDV(v5, used_m, 5)
                UPDV(v6, used_m, 6) UPDV(v7, used_m, 7)
                bool mine = (t == lane1);
                p0 = (mine && slot1 == 0) ? i : p0;
                p1 = (mine && slot1 == 1) ? i : p1;
                p2 = (mine && slot1 == 2) ? i : p2;
                p3 = (mine && slot1 == 3) ? i : p3;
                p4 = (mine && slot1 == 4) ? i : p4;
                p5 = (mine && slot1 == 5) ? i : p5;
                p6 = (mine && slot1 == 6) ? i : p6;
                p7 = (mine && slot1 == 7) ? i : p7;
                break;
            }

            // ---- hop: fetch next row scalars FIRST (serial chain), then
            // bookkeeping (off-chain; owner's u/chain untouched this step)
            ROW_SCALARS(owner);

            UPDU(u0, chain_m, 0) UPDU(u1, chain_m, 1)
            UPDU(u2, chain_m, 2) UPDU(u3, chain_m, 3)
            UPDU(u4, chain_m, 4) UPDU(u5, chain_m, 5)
            UPDU(u6, chain_m, 6) UPDU(u7, chain_m, 7)
            UPDV(v0, used_m, 0) UPDV(v1, used_m, 1)
            UPDV(v2, used_m, 2) UPDV(v3, used_m, 3)
            UPDV(v4, used_m, 4) UPDV(v5, used_m, 5)
            UPDV(v6, used_m, 6) UPDV(v7, used_m, 7)

            used_m  |= (t == lane1)        ? (1u << slot1)       : 0u;
            chain_m |= (t == (owner >> 3)) ? (1u << (owner & 7)) : 0u;
        }
    }

    // col_of_row[p_col[j]] = j   (j = 8t + k)
    gt_idx[b * N_ + p0] = (float)(base);
    gt_idx[b * N_ + p1] = (float)(base + 1);
    gt_idx[b * N_ + p2] = (float)(base + 2);
    gt_idx[b * N_ + p3] = (float)(base + 3);
    gt_idx[b * N_ + p4] = (float)(base + 4);
    gt_idx[b * N_ + p5] = (float)(base + 5);
    gt_idx[b * N_ + p6] = (float)(base + 6);
    gt_idx[b * N_ + p7] = (float)(base + 7);
}

// ---------------------------------------------------------------------------
extern "C" void kernel_launch(void* const* d_in, const int* in_sizes, int n_in,
                              void* d_out, int out_size, void* d_ws, size_t ws_size,
                              hipStream_t stream)
{
    const float* logits   = (const float*)d_in[0];   // (B,N)   f32
    const float* pred_pts = (const float*)d_in[1];   // (B,N,2) f32
    const float* gt_pts   = (const float*)d_in[2];   // (B,N,2) f32
    // d_in[3] = gt_mask (all true) - unused

    float* out      = (float*)d_out;
    float* pred_idx = out;                    // B*N
    float* gt_idx   = out + B_ * N_;          // B*N
    float* C        = out + 2 * B_ * N_;      // B*N*N
    float* cc       = (float*)d_ws;           // B*N scratch

    class_cost_kernel<<<(B_ * N_ + 255) / 256, 256, 0, stream>>>(logits, cc);
    cost_kernel<<<B_ * N_, N_, 0, stream>>>(cc, pred_pts, gt_pts, C);
    solve_kernel<<<B_, 64, 0, stream>>>(cc, pred_pts, gt_pts, pred_idx, gt_idx);
}